// Round 1
// baseline (717.205 us; speedup 1.0000x reference)
//
#include <hip/hip_runtime.h>
#include <math.h>

#define BLK 256

// ---------------------------------------------------------------------------
// GCNPolicyNetwork: 3-layer improved-GCN + masked softmax + mean-pool value.
// Strategy: build CSR (in-edges per target node) once per call, then each
// layer is a gather-accumulate (no fp32 atomics). Per layer we store only
// hws[n][f] = dinv[n] * (h @ W)[n][f]; then
//   h_next[n][f] = act( dinv[n]*( sum_{r in in(n)} hws[r][f] + 2*hws[n][f] ) + b[f] )
// which is algebraically identical to the reference gcn().
// ---------------------------------------------------------------------------

__global__ void k_degree(const int* __restrict__ col, int* __restrict__ degi, int E) {
    int e = blockIdx.x * blockDim.x + threadIdx.x;
    if (e < E) atomicAdd(&degi[col[e]], 1);
}

// per-block exclusive scan (within block) + block totals
__global__ void k_scan1(const int* __restrict__ degi, int* __restrict__ offs,
                        int* __restrict__ bsum, int n) {
    __shared__ int s[BLK];
    int tid = threadIdx.x;
    int i = blockIdx.x * BLK + tid;
    int v = (i < n) ? degi[i] : 0;
    s[tid] = v;
    __syncthreads();
    for (int d = 1; d < BLK; d <<= 1) {
        int t = (tid >= d) ? s[tid - d] : 0;
        __syncthreads();
        if (tid >= d) s[tid] += t;
        __syncthreads();
    }
    if (i < n) offs[i] = s[tid] - v;           // exclusive within block
    if (tid == BLK - 1) bsum[blockIdx.x] = s[tid];
}

// single-block exclusive scan of block sums (nblk <= 512)
__global__ void k_scan2(int* __restrict__ bsum, int nblk) {
    __shared__ int s[512];
    int tid = threadIdx.x;
    int v = (tid < nblk) ? bsum[tid] : 0;
    s[tid] = v;
    __syncthreads();
    for (int d = 1; d < 512; d <<= 1) {
        int t = (tid >= d) ? s[tid - d] : 0;
        __syncthreads();
        if (tid >= d) s[tid] += t;
        __syncthreads();
    }
    if (tid < nblk) bsum[tid] = s[tid] - v;    // exclusive
}

__global__ void k_scan3(const int* __restrict__ degi, int* __restrict__ offs,
                        int* __restrict__ cursor, float* __restrict__ dinv,
                        const int* __restrict__ bsum, int n) {
    int i = blockIdx.x * BLK + threadIdx.x;
    if (i < n) {
        int off = offs[i] + bsum[blockIdx.x];
        offs[i] = off;
        cursor[i] = off;
        dinv[i] = rsqrtf((float)degi[i] + 2.0f);
    }
}

__global__ void k_scatter(const int* __restrict__ row, const int* __restrict__ col,
                          int* __restrict__ cursor, int* __restrict__ srcs, int E) {
    int e = blockIdx.x * blockDim.x + threadIdx.x;
    if (e < E) {
        int c = col[e];
        int p = atomicAdd(&cursor[c], 1);
        srcs[p] = row[e];
    }
}

// layer-1 transform: hwsA = dinv * (x @ W1)   (x is N x 3)
__global__ void __launch_bounds__(BLK) k_l1(const float* __restrict__ x,
                                            const float* __restrict__ W1,
                                            const float* __restrict__ dinv,
                                            float* __restrict__ hwsA, int n) {
    __shared__ float w[48];
    if (threadIdx.x < 48) w[threadIdx.x] = W1[threadIdx.x];
    __syncthreads();
    int i = blockIdx.x * BLK + threadIdx.x;
    if (i >= n) return;
    float x0 = x[i * 3 + 0], x1 = x[i * 3 + 1], x2 = x[i * 3 + 2];
    float di = dinv[i];
#pragma unroll
    for (int f = 0; f < 16; f++) {
        float hw = x0 * w[f] + x1 * w[16 + f] + x2 * w[32 + f];
        hwsA[i * 16 + f] = di * hw;
    }
}

#define GATHER16(HWS, R, ACC)                                                   \
    {                                                                           \
        const float4* q = reinterpret_cast<const float4*>((HWS) + ((size_t)(R) << 4)); \
        float4 q0 = q[0], q1 = q[1], q2 = q[2], q3 = q[3];                      \
        ACC[0] += q0.x; ACC[1] += q0.y; ACC[2] += q0.z; ACC[3] += q0.w;         \
        ACC[4] += q1.x; ACC[5] += q1.y; ACC[6] += q1.z; ACC[7] += q1.w;         \
        ACC[8] += q2.x; ACC[9] += q2.y; ACC[10] += q2.z; ACC[11] += q2.w;       \
        ACC[12] += q3.x; ACC[13] += q3.y; ACC[14] += q3.z; ACC[15] += q3.w;     \
    }

// layer-1 aggregate + relu + layer-2 transform: hwsB = dinv * (h1 @ W2)
__global__ void __launch_bounds__(BLK) k_agg1(const float* __restrict__ hwsA,
                                              const int* __restrict__ offs,
                                              const int* __restrict__ degi,
                                              const int* __restrict__ srcs,
                                              const float* __restrict__ dinv,
                                              const float* __restrict__ b1,
                                              const float* __restrict__ W2,
                                              float* __restrict__ hwsB, int n) {
    __shared__ float w[256];
    __shared__ float bb[16];
    w[threadIdx.x] = W2[threadIdx.x];
    if (threadIdx.x < 16) bb[threadIdx.x] = b1[threadIdx.x];
    __syncthreads();
    int i = blockIdx.x * BLK + threadIdx.x;
    if (i >= n) return;
    float acc[16];
#pragma unroll
    for (int f = 0; f < 16; f++) acc[f] = 2.0f * hwsA[i * 16 + f];
    int beg = offs[i], end = beg + degi[i];
    for (int j = beg; j < end; j++) {
        int r = srcs[j];
        GATHER16(hwsA, r, acc);
    }
    float di = dinv[i];
    float h[16];
#pragma unroll
    for (int f = 0; f < 16; f++) {
        float v = di * acc[f] + bb[f];
        h[f] = v > 0.0f ? v : 0.0f;
    }
#pragma unroll
    for (int fo = 0; fo < 16; fo++) {
        float s = 0.0f;
#pragma unroll
        for (int f = 0; f < 16; f++) s += h[f] * w[f * 16 + fo];
        hwsB[i * 16 + fo] = di * s;
    }
}

// layer-2 aggregate + relu (-> h2), pool accumulation, layer-3 transform
__global__ void __launch_bounds__(BLK) k_agg2(const float* __restrict__ hwsB,
                                              const int* __restrict__ offs,
                                              const int* __restrict__ degi,
                                              const int* __restrict__ srcs,
                                              const float* __restrict__ dinv,
                                              const float* __restrict__ b2,
                                              const float* __restrict__ W3,
                                              float* __restrict__ hws3,
                                              float* __restrict__ pool, int n) {
    __shared__ float w3[16];
    __shared__ float bb[16];
    __shared__ float lp[16];
    if (threadIdx.x < 16) {
        w3[threadIdx.x] = W3[threadIdx.x];
        bb[threadIdx.x] = b2[threadIdx.x];
        lp[threadIdx.x] = 0.0f;
    }
    __syncthreads();
    int i = blockIdx.x * BLK + threadIdx.x;
    if (i < n) {
        float acc[16];
#pragma unroll
        for (int f = 0; f < 16; f++) acc[f] = 2.0f * hwsB[i * 16 + f];
        int beg = offs[i], end = beg + degi[i];
        for (int j = beg; j < end; j++) {
            int r = srcs[j];
            GATHER16(hwsB, r, acc);
        }
        float di = dinv[i];
        float hw3 = 0.0f;
#pragma unroll
        for (int f = 0; f < 16; f++) {
            float v = di * acc[f] + bb[f];
            float h = v > 0.0f ? v : 0.0f;
            hw3 += h * w3[f];
            atomicAdd(&lp[f], h);
        }
        hws3[i] = di * hw3;
    }
    __syncthreads();
    if (threadIdx.x < 16) atomicAdd(&pool[threadIdx.x], lp[threadIdx.x]);
}

// layer-3 aggregate -> logits c[n]; per-block max of masked logits
__global__ void __launch_bounds__(BLK) k_agg3(const float* __restrict__ hws3,
                                              const int* __restrict__ offs,
                                              const int* __restrict__ degi,
                                              const int* __restrict__ srcs,
                                              const float* __restrict__ dinv,
                                              const float* __restrict__ b3,
                                              const int* __restrict__ choices,
                                              float* __restrict__ cbuf,
                                              float* __restrict__ pmax, int n) {
    __shared__ float red[BLK];
    int i = blockIdx.x * BLK + threadIdx.x;
    float logit = -INFINITY;
    if (i < n) {
        float s = 2.0f * hws3[i];
        int beg = offs[i], end = beg + degi[i];
        for (int j = beg; j < end; j++) s += hws3[srcs[j]];
        float c = dinv[i] * s + b3[0];
        cbuf[i] = c;
        if (choices[i] != 0) logit = c;
    }
    red[threadIdx.x] = logit;
    __syncthreads();
    for (int d = BLK / 2; d > 0; d >>= 1) {
        if (threadIdx.x < d) red[threadIdx.x] = fmaxf(red[threadIdx.x], red[threadIdx.x + d]);
        __syncthreads();
    }
    if (threadIdx.x == 0) pmax[blockIdx.x] = red[0];
}

__global__ void k_redmax(const float* __restrict__ pmax, float* __restrict__ scal_m, int nblk) {
    __shared__ float red[BLK];
    float m = -INFINITY;
    for (int i = threadIdx.x; i < nblk; i += BLK) m = fmaxf(m, pmax[i]);
    red[threadIdx.x] = m;
    __syncthreads();
    for (int d = BLK / 2; d > 0; d >>= 1) {
        if (threadIdx.x < d) red[threadIdx.x] = fmaxf(red[threadIdx.x], red[threadIdx.x + d]);
        __syncthreads();
    }
    if (threadIdx.x == 0) scal_m[0] = red[0];
}

__global__ void __launch_bounds__(BLK) k_sumexp(const float* __restrict__ cbuf,
                                                const int* __restrict__ choices,
                                                const float* __restrict__ scal_m,
                                                float* __restrict__ Ssum, int n) {
    __shared__ float red[BLK];
    int i = blockIdx.x * BLK + threadIdx.x;
    float m = scal_m[0];
    float v = 0.0f;
    if (i < n && choices[i] != 0) v = expf(cbuf[i] - m);
    red[threadIdx.x] = v;
    __syncthreads();
    for (int d = BLK / 2; d > 0; d >>= 1) {
        if (threadIdx.x < d) red[threadIdx.x] += red[threadIdx.x + d];
        __syncthreads();
    }
    if (threadIdx.x == 0) atomicAdd(Ssum, red[0]);
}

__global__ void __launch_bounds__(BLK) k_final(const float* __restrict__ cbuf,
                                               const int* __restrict__ choices,
                                               const float* __restrict__ scal_m,
                                               const float* __restrict__ Ssum,
                                               const float* __restrict__ pool,
                                               const float* __restrict__ fcw,
                                               const float* __restrict__ fcb,
                                               float* __restrict__ out, int n) {
    int i = blockIdx.x * BLK + threadIdx.x;
    if (i < n) {
        float p = 0.0f;
        if (choices[i] != 0) {
            float m = scal_m[0], S = Ssum[0];
            p = expf(cbuf[i] - m) / S;
        }
        out[i] = p;
    }
    if (blockIdx.x == 0 && threadIdx.x == 0) {
        float invn = 1.0f / (float)n;
        float v = 0.0f;
#pragma unroll
        for (int f = 0; f < 16; f++) v += (pool[f] * invn) * fcw[f];
        out[n] = v + fcb[0];
    }
}

extern "C" void kernel_launch(void* const* d_in, const int* in_sizes, int n_in,
                              void* d_out, int out_size, void* d_ws, size_t ws_size,
                              hipStream_t stream) {
    const float* x       = (const float*)d_in[0];
    const int*   ei      = (const int*)d_in[1];
    const int*   choices = (const int*)d_in[2];
    const float* W1 = (const float*)d_in[3];
    const float* b1 = (const float*)d_in[4];
    const float* W2 = (const float*)d_in[5];
    const float* b2 = (const float*)d_in[6];
    const float* W3 = (const float*)d_in[7];
    const float* b3 = (const float*)d_in[8];
    const float* fcw = (const float*)d_in[9];
    const float* fcb = (const float*)d_in[10];
    float* out = (float*)d_out;

    int n = in_sizes[0] / 3;
    int E = in_sizes[1] / 2;
    const int* row = ei;
    const int* col = ei + E;

    int nblkN = (n + BLK - 1) / BLK;   // 391 for n=100000 (must be <= 512 for k_scan2)
    int nblkE = (E + BLK - 1) / BLK;

    // workspace layout (16B aligned slices)
    char* ws = (char*)d_ws;
    size_t o = 0;
    auto alloc = [&](size_t bytes) { char* p = ws + o; o += (bytes + 15) & ~(size_t)15; return p; };
    int*   degi   = (int*)  alloc((size_t)n * 4);
    int*   offs   = (int*)  alloc((size_t)n * 4);
    int*   cursor = (int*)  alloc((size_t)n * 4);
    float* dinv   = (float*)alloc((size_t)n * 4);
    float* hws3   = (float*)alloc((size_t)n * 4);
    float* cbuf   = (float*)alloc((size_t)n * 4);
    float* pmax   = (float*)alloc(4096);
    int*   bsum   = (int*)  alloc(4096);
    float* scal   = (float*)alloc(256);   // [0]=S, [1..16]=pool, [17]=m
    float* Ssum   = scal + 0;
    float* pool   = scal + 1;
    float* scal_m = scal + 17;
    float* hwsA   = (float*)alloc((size_t)n * 16 * 4);
    float* hwsB   = (float*)alloc((size_t)n * 16 * 4);
    int*   srcs   = (int*)  alloc((size_t)E * 4);
    (void)ws_size; // ~28.5 MB used

    hipMemsetAsync(degi, 0, (size_t)n * 4, stream);
    hipMemsetAsync(scal, 0, 68, stream);   // S + pool[16]

    k_degree<<<nblkE, BLK, 0, stream>>>(col, degi, E);
    k_scan1<<<nblkN, BLK, 0, stream>>>(degi, offs, bsum, n);
    k_scan2<<<1, 512, 0, stream>>>(bsum, nblkN);
    k_scan3<<<nblkN, BLK, 0, stream>>>(degi, offs, cursor, dinv, bsum, n);
    k_scatter<<<nblkE, BLK, 0, stream>>>(row, col, cursor, srcs, E);

    k_l1<<<nblkN, BLK, 0, stream>>>(x, W1, dinv, hwsA, n);
    k_agg1<<<nblkN, BLK, 0, stream>>>(hwsA, offs, degi, srcs, dinv, b1, W2, hwsB, n);
    k_agg2<<<nblkN, BLK, 0, stream>>>(hwsB, offs, degi, srcs, dinv, b2, W3, hws3, pool, n);
    k_agg3<<<nblkN, BLK, 0, stream>>>(hws3, offs, degi, srcs, dinv, b3, choices, cbuf, pmax, n);
    k_redmax<<<1, BLK, 0, stream>>>(pmax, scal_m, nblkN);
    k_sumexp<<<nblkN, BLK, 0, stream>>>(cbuf, choices, scal_m, Ssum, n);
    k_final<<<nblkN, BLK, 0, stream>>>(cbuf, choices, scal_m, Ssum, pool, fcw, fcb, out, n);
}

// Round 2
// 491.456 us; speedup vs baseline: 1.4593x; 1.4593x over previous
//
#include <hip/hip_runtime.h>
#include <math.h>

#define BLK 256

// ---------------------------------------------------------------------------
// GCNPolicyNetwork: 3-layer improved-GCN + masked softmax + mean-pool value.
// CSR built per call. Round 2: replaced random-scatter CSR build (195 MB HBM
// writeback from 4B random writes) with 2-pass bucketed multisplit:
//   k_bin  : LDS multisplit into 512-node buckets, coalesced run flush
//   k_place: per-bucket fine placement, writes confined to ~64KB L2 window
// Edge packed as (row<<9)|(col&511) (row<2^17 ok for N=100k? 100000<131072 yes).
// packed[] aliases the hwsA/hwsB region (only used after the build completes).
// ---------------------------------------------------------------------------

#define BSH 9                    // 512 nodes per bucket
#define EB 8192                  // edges per k_bin block
#define BINTH 512                // k_bin block size

__global__ void k_degree(const int* __restrict__ col, int* __restrict__ degi, int E) {
    int e = blockIdx.x * blockDim.x + threadIdx.x;
    if (e < E) atomicAdd(&degi[col[e]], 1);
}

// per-block exclusive scan (within block) + block totals
__global__ void k_scan1(const int* __restrict__ degi, int* __restrict__ offs,
                        int* __restrict__ bsum, int n) {
    __shared__ int s[BLK];
    int tid = threadIdx.x;
    int i = blockIdx.x * BLK + tid;
    int v = (i < n) ? degi[i] : 0;
    s[tid] = v;
    __syncthreads();
    for (int d = 1; d < BLK; d <<= 1) {
        int t = (tid >= d) ? s[tid - d] : 0;
        __syncthreads();
        if (tid >= d) s[tid] += t;
        __syncthreads();
    }
    if (i < n) offs[i] = s[tid] - v;           // exclusive within block
    if (tid == BLK - 1) bsum[blockIdx.x] = s[tid];
}

// single-block exclusive scan of block sums (nblk <= 512)
__global__ void k_scan2(int* __restrict__ bsum, int nblk) {
    __shared__ int s[512];
    int tid = threadIdx.x;
    int v = (tid < nblk) ? bsum[tid] : 0;
    s[tid] = v;
    __syncthreads();
    for (int d = 1; d < 512; d <<= 1) {
        int t = (tid >= d) ? s[tid - d] : 0;
        __syncthreads();
        if (tid >= d) s[tid] += t;
        __syncthreads();
    }
    if (tid < nblk) bsum[tid] = s[tid] - v;    // exclusive
}

__global__ void k_scan3(const int* __restrict__ degi, int* __restrict__ offs,
                        float* __restrict__ dinv,
                        const int* __restrict__ bsum, int n) {
    int i = blockIdx.x * BLK + threadIdx.x;
    if (i < n) {
        int off = offs[i] + bsum[blockIdx.x];
        offs[i] = off;
        dinv[i] = rsqrtf((float)degi[i] + 2.0f);
    }
}

// init bucket cursors: gcur[b] = CSR offset of first node in bucket b
__global__ void k_initcur(const int* __restrict__ offs, int* __restrict__ gcur,
                          int nbuck, int n, int E) {
    int b = blockIdx.x * blockDim.x + threadIdx.x;
    if (b < nbuck) {
        int node = b << BSH;
        gcur[b] = (node < n) ? offs[node] : E;
    }
}

// pass 1: LDS multisplit of edges into buckets, coalesced flush to packed[]
__global__ void __launch_bounds__(BINTH) k_bin(const int* __restrict__ row,
                                               const int* __restrict__ col,
                                               int* __restrict__ gcur,
                                               int* __restrict__ packed, int E) {
    __shared__ int stage[EB];            // packed edges, bucket-sorted locally
    __shared__ unsigned char sbuk[EB];   // bucket id per staged slot
    __shared__ int hist[256];
    __shared__ int lscan[256];
    __shared__ int cur[256];
    __shared__ int gbase[256];
    int tid = threadIdx.x;
    int base = blockIdx.x * EB;
    int cnt = min(EB, E - base);

    if (tid < 256) hist[tid] = 0;
    __syncthreads();
    for (int j = tid; j < cnt; j += BINTH) {
        int c = col[base + j];
        atomicAdd(&hist[c >> BSH], 1);
    }
    __syncthreads();
    // exclusive scan of hist -> lscan, copy to cur
    if (tid < 256) lscan[tid] = hist[tid];
    __syncthreads();
    for (int d = 1; d < 256; d <<= 1) {
        int t = 0;
        if (tid < 256 && tid >= d) t = lscan[tid - d];
        __syncthreads();
        if (tid < 256 && tid >= d) lscan[tid] += t;
        __syncthreads();
    }
    if (tid < 256) {
        int ex = lscan[tid] - hist[tid];
        lscan[tid] = ex;
        cur[tid] = ex;
    }
    __syncthreads();
    // stage edges into bucket-sorted LDS order
    for (int j = tid; j < cnt; j += BINTH) {
        int c = col[base + j];
        int r = row[base + j];
        int b = c >> BSH;
        int p = atomicAdd(&cur[b], 1);
        stage[p] = (r << BSH) | (c & ((1 << BSH) - 1));
        sbuk[p] = (unsigned char)b;
    }
    __syncthreads();
    // reserve global ranges (one atomic per non-empty bucket per block)
    if (tid < 256 && hist[tid] > 0) gbase[tid] = atomicAdd(&gcur[tid], hist[tid]);
    __syncthreads();
    // flush: consecutive j in a bucket -> consecutive global pos (coalesced runs)
    for (int j = tid; j < cnt; j += BINTH) {
        int b = sbuk[j];
        int pos = gbase[b] + (j - lscan[b]);
        packed[pos] = stage[j];
    }
}

// pass 2: per-bucket fine placement; writes confined to bucket's srcs window
__global__ void __launch_bounds__(BLK) k_place(const int* __restrict__ packed,
                                               const int* __restrict__ offs,
                                               int* __restrict__ srcs, int n, int E) {
    __shared__ int lcur[1 << BSH];
    __shared__ int loff[1 << BSH];
    int tid = threadIdx.x;
    int nb0 = blockIdx.x << BSH;
    int nb1 = min(nb0 + (1 << BSH), n);
    for (int t = tid; t < (1 << BSH); t += BLK) {
        lcur[t] = 0;
        loff[t] = (nb0 + t < n) ? offs[nb0 + t] : 0;
    }
    __syncthreads();
    int pbeg = offs[nb0];
    int pend = (nb1 < n) ? offs[nb1] : E;
    for (int j = pbeg + tid; j < pend; j += BLK) {
        int v = packed[j];
        int li = v & ((1 << BSH) - 1);
        int r = v >> BSH;
        int slot = atomicAdd(&lcur[li], 1);
        srcs[loff[li] + slot] = r;
    }
}

// layer-1 transform: hwsA = dinv * (x @ W1)   (x is N x 3)
__global__ void __launch_bounds__(BLK) k_l1(const float* __restrict__ x,
                                            const float* __restrict__ W1,
                                            const float* __restrict__ dinv,
                                            float* __restrict__ hwsA, int n) {
    __shared__ float w[48];
    if (threadIdx.x < 48) w[threadIdx.x] = W1[threadIdx.x];
    __syncthreads();
    int i = blockIdx.x * BLK + threadIdx.x;
    if (i >= n) return;
    float x0 = x[i * 3 + 0], x1 = x[i * 3 + 1], x2 = x[i * 3 + 2];
    float di = dinv[i];
#pragma unroll
    for (int f = 0; f < 16; f++) {
        float hw = x0 * w[f] + x1 * w[16 + f] + x2 * w[32 + f];
        hwsA[i * 16 + f] = di * hw;
    }
}

#define GATHER16(HWS, R, ACC)                                                   \
    {                                                                           \
        const float4* q = reinterpret_cast<const float4*>((HWS) + ((size_t)(R) << 4)); \
        float4 q0 = q[0], q1 = q[1], q2 = q[2], q3 = q[3];                      \
        ACC[0] += q0.x; ACC[1] += q0.y; ACC[2] += q0.z; ACC[3] += q0.w;         \
        ACC[4] += q1.x; ACC[5] += q1.y; ACC[6] += q1.z; ACC[7] += q1.w;         \
        ACC[8] += q2.x; ACC[9] += q2.y; ACC[10] += q2.z; ACC[11] += q2.w;       \
        ACC[12] += q3.x; ACC[13] += q3.y; ACC[14] += q3.z; ACC[15] += q3.w;     \
    }

// layer-1 aggregate + relu + layer-2 transform: hwsB = dinv * (h1 @ W2)
__global__ void __launch_bounds__(BLK) k_agg1(const float* __restrict__ hwsA,
                                              const int* __restrict__ offs,
                                              const int* __restrict__ degi,
                                              const int* __restrict__ srcs,
                                              const float* __restrict__ dinv,
                                              const float* __restrict__ b1,
                                              const float* __restrict__ W2,
                                              float* __restrict__ hwsB, int n) {
    __shared__ float w[256];
    __shared__ float bb[16];
    w[threadIdx.x] = W2[threadIdx.x];
    if (threadIdx.x < 16) bb[threadIdx.x] = b1[threadIdx.x];
    __syncthreads();
    int i = blockIdx.x * BLK + threadIdx.x;
    if (i >= n) return;
    float acc[16];
#pragma unroll
    for (int f = 0; f < 16; f++) acc[f] = 2.0f * hwsA[i * 16 + f];
    int beg = offs[i], end = beg + degi[i];
    for (int j = beg; j < end; j++) {
        int r = srcs[j];
        GATHER16(hwsA, r, acc);
    }
    float di = dinv[i];
    float h[16];
#pragma unroll
    for (int f = 0; f < 16; f++) {
        float v = di * acc[f] + bb[f];
        h[f] = v > 0.0f ? v : 0.0f;
    }
#pragma unroll
    for (int fo = 0; fo < 16; fo++) {
        float s = 0.0f;
#pragma unroll
        for (int f = 0; f < 16; f++) s += h[f] * w[f * 16 + fo];
        hwsB[i * 16 + fo] = di * s;
    }
}

// layer-2 aggregate + relu (-> h2), pool accumulation, layer-3 transform
__global__ void __launch_bounds__(BLK) k_agg2(const float* __restrict__ hwsB,
                                              const int* __restrict__ offs,
                                              const int* __restrict__ degi,
                                              const int* __restrict__ srcs,
                                              const float* __restrict__ dinv,
                                              const float* __restrict__ b2,
                                              const float* __restrict__ W3,
                                              float* __restrict__ hws3,
                                              float* __restrict__ pool, int n) {
    __shared__ float w3[16];
    __shared__ float bb[16];
    __shared__ float lp[16];
    if (threadIdx.x < 16) {
        w3[threadIdx.x] = W3[threadIdx.x];
        bb[threadIdx.x] = b2[threadIdx.x];
        lp[threadIdx.x] = 0.0f;
    }
    __syncthreads();
    int i = blockIdx.x * BLK + threadIdx.x;
    if (i < n) {
        float acc[16];
#pragma unroll
        for (int f = 0; f < 16; f++) acc[f] = 2.0f * hwsB[i * 16 + f];
        int beg = offs[i], end = beg + degi[i];
        for (int j = beg; j < end; j++) {
            int r = srcs[j];
            GATHER16(hwsB, r, acc);
        }
        float di = dinv[i];
        float hw3 = 0.0f;
#pragma unroll
        for (int f = 0; f < 16; f++) {
            float v = di * acc[f] + bb[f];
            float h = v > 0.0f ? v : 0.0f;
            hw3 += h * w3[f];
            atomicAdd(&lp[f], h);
        }
        hws3[i] = di * hw3;
    }
    __syncthreads();
    if (threadIdx.x < 16) atomicAdd(&pool[threadIdx.x], lp[threadIdx.x]);
}

// layer-3 aggregate -> logits c[n]; per-block max of masked logits
__global__ void __launch_bounds__(BLK) k_agg3(const float* __restrict__ hws3,
                                              const int* __restrict__ offs,
                                              const int* __restrict__ degi,
                                              const int* __restrict__ srcs,
                                              const float* __restrict__ dinv,
                                              const float* __restrict__ b3,
                                              const int* __restrict__ choices,
                                              float* __restrict__ cbuf,
                                              float* __restrict__ pmax, int n) {
    __shared__ float red[BLK];
    int i = blockIdx.x * BLK + threadIdx.x;
    float logit = -INFINITY;
    if (i < n) {
        float s = 2.0f * hws3[i];
        int beg = offs[i], end = beg + degi[i];
        for (int j = beg; j < end; j++) s += hws3[srcs[j]];
        float c = dinv[i] * s + b3[0];
        cbuf[i] = c;
        if (choices[i] != 0) logit = c;
    }
    red[threadIdx.x] = logit;
    __syncthreads();
    for (int d = BLK / 2; d > 0; d >>= 1) {
        if (threadIdx.x < d) red[threadIdx.x] = fmaxf(red[threadIdx.x], red[threadIdx.x + d]);
        __syncthreads();
    }
    if (threadIdx.x == 0) pmax[blockIdx.x] = red[0];
}

__global__ void k_redmax(const float* __restrict__ pmax, float* __restrict__ scal_m, int nblk) {
    __shared__ float red[BLK];
    float m = -INFINITY;
    for (int i = threadIdx.x; i < nblk; i += BLK) m = fmaxf(m, pmax[i]);
    red[threadIdx.x] = m;
    __syncthreads();
    for (int d = BLK / 2; d > 0; d >>= 1) {
        if (threadIdx.x < d) red[threadIdx.x] = fmaxf(red[threadIdx.x], red[threadIdx.x + d]);
        __syncthreads();
    }
    if (threadIdx.x == 0) scal_m[0] = red[0];
}

__global__ void __launch_bounds__(BLK) k_sumexp(const float* __restrict__ cbuf,
                                                const int* __restrict__ choices,
                                                const float* __restrict__ scal_m,
                                                float* __restrict__ Ssum, int n) {
    __shared__ float red[BLK];
    int i = blockIdx.x * BLK + threadIdx.x;
    float m = scal_m[0];
    float v = 0.0f;
    if (i < n && choices[i] != 0) v = expf(cbuf[i] - m);
    red[threadIdx.x] = v;
    __syncthreads();
    for (int d = BLK / 2; d > 0; d >>= 1) {
        if (threadIdx.x < d) red[threadIdx.x] += red[threadIdx.x + d];
        __syncthreads();
    }
    if (threadIdx.x == 0) atomicAdd(Ssum, red[0]);
}

__global__ void __launch_bounds__(BLK) k_final(const float* __restrict__ cbuf,
                                               const int* __restrict__ choices,
                                               const float* __restrict__ scal_m,
                                               const float* __restrict__ Ssum,
                                               const float* __restrict__ pool,
                                               const float* __restrict__ fcw,
                                               const float* __restrict__ fcb,
                                               float* __restrict__ out, int n) {
    int i = blockIdx.x * BLK + threadIdx.x;
    if (i < n) {
        float p = 0.0f;
        if (choices[i] != 0) {
            float m = scal_m[0], S = Ssum[0];
            p = expf(cbuf[i] - m) / S;
        }
        out[i] = p;
    }
    if (blockIdx.x == 0 && threadIdx.x == 0) {
        float invn = 1.0f / (float)n;
        float v = 0.0f;
#pragma unroll
        for (int f = 0; f < 16; f++) v += (pool[f] * invn) * fcw[f];
        out[n] = v + fcb[0];
    }
}

extern "C" void kernel_launch(void* const* d_in, const int* in_sizes, int n_in,
                              void* d_out, int out_size, void* d_ws, size_t ws_size,
                              hipStream_t stream) {
    const float* x       = (const float*)d_in[0];
    const int*   ei      = (const int*)d_in[1];
    const int*   choices = (const int*)d_in[2];
    const float* W1 = (const float*)d_in[3];
    const float* b1 = (const float*)d_in[4];
    const float* W2 = (const float*)d_in[5];
    const float* b2 = (const float*)d_in[6];
    const float* W3 = (const float*)d_in[7];
    const float* b3 = (const float*)d_in[8];
    const float* fcw = (const float*)d_in[9];
    const float* fcb = (const float*)d_in[10];
    float* out = (float*)d_out;

    int n = in_sizes[0] / 3;
    int E = in_sizes[1] / 2;
    const int* row = ei;
    const int* col = ei + E;

    int nblkN = (n + BLK - 1) / BLK;   // 391 for n=100000 (must be <= 512 for k_scan2)
    int nblkE = (E + BLK - 1) / BLK;
    int nbuck = (n + (1 << BSH) - 1) >> BSH;   // 196 buckets of 512 nodes
    int nblkBin = (E + EB - 1) / EB;           // 391 multisplit blocks

    // workspace layout (16B aligned slices)
    char* ws = (char*)d_ws;
    size_t o = 0;
    auto alloc = [&](size_t bytes) { char* p = ws + o; o += (bytes + 15) & ~(size_t)15; return p; };
    int*   degi   = (int*)  alloc((size_t)n * 4);
    int*   offs   = (int*)  alloc((size_t)n * 4);
    float* dinv   = (float*)alloc((size_t)n * 4);
    float* hws3   = (float*)alloc((size_t)n * 4);
    float* cbuf   = (float*)alloc((size_t)n * 4);
    float* pmax   = (float*)alloc(4096);
    int*   bsum   = (int*)  alloc(4096);
    int*   gcur   = (int*)  alloc(4096);
    float* scal   = (float*)alloc(256);   // [0]=S, [1..16]=pool, [17]=m
    float* Ssum   = scal + 0;
    float* pool   = scal + 1;
    float* scal_m = scal + 17;
    size_t hw_bytes = (size_t)n * 16 * 4 * 2;            // hwsA + hwsB
    size_t pk_bytes = (size_t)E * 4;                     // packed (aliases hwsA/B)
    char*  blob   = alloc(hw_bytes > pk_bytes ? hw_bytes : pk_bytes);
    float* hwsA   = (float*)blob;
    float* hwsB   = hwsA + (size_t)n * 16;
    int*   packed = (int*)blob;           // build phase only; dead before k_l1
    int*   srcs   = (int*)  alloc((size_t)E * 4);
    (void)ws_size; // ~28.5 MB used

    hipMemsetAsync(degi, 0, (size_t)n * 4, stream);
    hipMemsetAsync(scal, 0, 68, stream);   // S + pool[16]

    // ---- CSR build ----
    k_degree<<<nblkE, BLK, 0, stream>>>(col, degi, E);
    k_scan1<<<nblkN, BLK, 0, stream>>>(degi, offs, bsum, n);
    k_scan2<<<1, 512, 0, stream>>>(bsum, nblkN);
    k_scan3<<<nblkN, BLK, 0, stream>>>(degi, offs, dinv, bsum, n);
    k_initcur<<<1, 256, 0, stream>>>(offs, gcur, nbuck, n, E);
    k_bin<<<nblkBin, BINTH, 0, stream>>>(row, col, gcur, packed, E);
    k_place<<<nbuck, BLK, 0, stream>>>(packed, offs, srcs, n, E);

    // ---- GCN layers ----
    k_l1<<<nblkN, BLK, 0, stream>>>(x, W1, dinv, hwsA, n);
    k_agg1<<<nblkN, BLK, 0, stream>>>(hwsA, offs, degi, srcs, dinv, b1, W2, hwsB, n);
    k_agg2<<<nblkN, BLK, 0, stream>>>(hwsB, offs, degi, srcs, dinv, b2, W3, hws3, pool, n);
    k_agg3<<<nblkN, BLK, 0, stream>>>(hws3, offs, degi, srcs, dinv, b3, choices, cbuf, pmax, n);

    // ---- softmax + value head ----
    k_redmax<<<1, BLK, 0, stream>>>(pmax, scal_m, nblkN);
    k_sumexp<<<nblkN, BLK, 0, stream>>>(cbuf, choices, scal_m, Ssum, n);
    k_final<<<nblkN, BLK, 0, stream>>>(cbuf, choices, scal_m, Ssum, pool, fcw, fcb, out, n);
}

// Round 3
// 389.947 us; speedup vs baseline: 1.8392x; 1.2603x over previous
//
#include <hip/hip_runtime.h>
#include <math.h>

#define BLK 256

// ---------------------------------------------------------------------------
// GCNPolicyNetwork: 3-layer improved-GCN + masked softmax + mean-pool value.
// Round 3: removed ALL per-edge global atomics. The old k_degree (3.2M
// memory-side atomics = ~100 MB WRITE_SIZE, 127 us) is gone; degrees/offsets
// are now computed bucket-locally inside the multisplit:
//   k_bcount: LDS histogram of bucket ids -> <=196 atomics/block
//   k_bscan : scan 196 bucket counts -> bucket bases
//   k_bin   : LDS multisplit into 512-node buckets, coalesced run flush
//   k_place : per-bucket node-degree count + LDS scan -> degi/offs/dinv,
//             then fine placement into the bucket's srcs window (L2-resident)
// ---------------------------------------------------------------------------

#define BSH 9                    // 512 nodes per bucket
#define EB 8192                  // edges per binning block
#define BINTH 512                // k_bin block size

// per-block LDS histogram of bucket ids, flush with <=196 global atomics
__global__ void __launch_bounds__(BLK) k_bcount(const int* __restrict__ col,
                                                int* __restrict__ bcnt, int E) {
    __shared__ int hist[256];
    int tid = threadIdx.x;
    int base = blockIdx.x * EB;
    int cnt = min(EB, E - base);
    hist[tid] = 0;
    __syncthreads();
    for (int j = tid; j < cnt; j += BLK)
        atomicAdd(&hist[col[base + j] >> BSH], 1);
    __syncthreads();
    if (hist[tid] > 0) atomicAdd(&bcnt[tid], hist[tid]);
}

// single-block exclusive scan of bucket counts -> gcur (mutable) + bbase (kept)
__global__ void k_bscan(const int* __restrict__ bcnt, int* __restrict__ gcur,
                        int* __restrict__ bbase, int nbuck) {
    __shared__ int s[256];
    int tid = threadIdx.x;
    int v = (tid < nbuck) ? bcnt[tid] : 0;
    s[tid] = v;
    __syncthreads();
    for (int d = 1; d < 256; d <<= 1) {
        int t = (tid >= d) ? s[tid - d] : 0;
        __syncthreads();
        if (tid >= d) s[tid] += t;
        __syncthreads();
    }
    int ex = s[tid] - v;
    gcur[tid] = ex;
    bbase[tid] = ex;
}

// pass 1: LDS multisplit of edges into buckets, coalesced flush to packed[]
__global__ void __launch_bounds__(BINTH) k_bin(const int* __restrict__ row,
                                               const int* __restrict__ col,
                                               int* __restrict__ gcur,
                                               int* __restrict__ packed, int E) {
    __shared__ int stage[EB];            // packed edges, bucket-sorted locally
    __shared__ unsigned char sbuk[EB];   // bucket id per staged slot
    __shared__ int hist[256];
    __shared__ int lscan[256];
    __shared__ int cur[256];
    __shared__ int gbase[256];
    int tid = threadIdx.x;
    int base = blockIdx.x * EB;
    int cnt = min(EB, E - base);

    if (tid < 256) hist[tid] = 0;
    __syncthreads();
    for (int j = tid; j < cnt; j += BINTH) {
        int c = col[base + j];
        atomicAdd(&hist[c >> BSH], 1);
    }
    __syncthreads();
    if (tid < 256) lscan[tid] = hist[tid];
    __syncthreads();
    for (int d = 1; d < 256; d <<= 1) {
        int t = 0;
        if (tid < 256 && tid >= d) t = lscan[tid - d];
        __syncthreads();
        if (tid < 256 && tid >= d) lscan[tid] += t;
        __syncthreads();
    }
    if (tid < 256) {
        int ex = lscan[tid] - hist[tid];
        lscan[tid] = ex;
        cur[tid] = ex;
    }
    __syncthreads();
    for (int j = tid; j < cnt; j += BINTH) {
        int c = col[base + j];
        int r = row[base + j];
        int b = c >> BSH;
        int p = atomicAdd(&cur[b], 1);
        stage[p] = (r << BSH) | (c & ((1 << BSH) - 1));
        sbuk[p] = (unsigned char)b;
    }
    __syncthreads();
    if (tid < 256 && hist[tid] > 0) gbase[tid] = atomicAdd(&gcur[tid], hist[tid]);
    __syncthreads();
    for (int j = tid; j < cnt; j += BINTH) {
        int b = sbuk[j];
        int pos = gbase[b] + (j - lscan[b]);
        packed[pos] = stage[j];
    }
}

// pass 2: per-bucket degree count + scan (-> degi/offs/dinv) + fine placement
__global__ void __launch_bounds__(BLK) k_place(const int* __restrict__ packed,
                                               const int* __restrict__ bbase,
                                               const int* __restrict__ bcnt,
                                               int* __restrict__ degi,
                                               int* __restrict__ offs,
                                               float* __restrict__ dinv,
                                               int* __restrict__ srcs, int n) {
    __shared__ int cnt[1 << BSH];
    __shared__ int lcur[1 << BSH];
    __shared__ int ssum[BLK];
    int tid = threadIdx.x;
    int b = blockIdx.x;
    int nb0 = b << BSH;
    for (int t = tid; t < (1 << BSH); t += BLK) cnt[t] = 0;
    __syncthreads();
    int pbeg = bbase[b];
    int pend = pbeg + bcnt[b];
    for (int j = pbeg + tid; j < pend; j += BLK)
        atomicAdd(&cnt[packed[j] & ((1 << BSH) - 1)], 1);
    __syncthreads();
    // exclusive scan of 512 counts (2 per thread)
    int c0 = cnt[2 * tid], c1 = cnt[2 * tid + 1];
    int pair = c0 + c1;
    ssum[tid] = pair;
    __syncthreads();
    for (int d = 1; d < BLK; d <<= 1) {
        int t = (tid >= d) ? ssum[tid - d] : 0;
        __syncthreads();
        if (tid >= d) ssum[tid] += t;
        __syncthreads();
    }
    int ex = ssum[tid] - pair;
    lcur[2 * tid] = ex;
    lcur[2 * tid + 1] = ex + c0;
    int node0 = nb0 + 2 * tid;
    if (node0 < n) {
        degi[node0] = c0;
        offs[node0] = pbeg + ex;
        dinv[node0] = rsqrtf((float)c0 + 2.0f);
    }
    if (node0 + 1 < n) {
        degi[node0 + 1] = c1;
        offs[node0 + 1] = pbeg + ex + c0;
        dinv[node0 + 1] = rsqrtf((float)c1 + 2.0f);
    }
    __syncthreads();
    for (int j = pbeg + tid; j < pend; j += BLK) {
        int v = packed[j];
        int li = v & ((1 << BSH) - 1);
        int r = v >> BSH;
        int slot = atomicAdd(&lcur[li], 1);
        srcs[pbeg + slot] = r;
    }
}

// layer-1 transform: hwsA = dinv * (x @ W1)   (x is N x 3)
__global__ void __launch_bounds__(BLK) k_l1(const float* __restrict__ x,
                                            const float* __restrict__ W1,
                                            const float* __restrict__ dinv,
                                            float* __restrict__ hwsA, int n) {
    __shared__ float w[48];
    if (threadIdx.x < 48) w[threadIdx.x] = W1[threadIdx.x];
    __syncthreads();
    int i = blockIdx.x * BLK + threadIdx.x;
    if (i >= n) return;
    float x0 = x[i * 3 + 0], x1 = x[i * 3 + 1], x2 = x[i * 3 + 2];
    float di = dinv[i];
#pragma unroll
    for (int f = 0; f < 16; f++) {
        float hw = x0 * w[f] + x1 * w[16 + f] + x2 * w[32 + f];
        hwsA[i * 16 + f] = di * hw;
    }
}

#define GATHER16(HWS, R, ACC)                                                   \
    {                                                                           \
        const float4* q = reinterpret_cast<const float4*>((HWS) + ((size_t)(R) << 4)); \
        float4 q0 = q[0], q1 = q[1], q2 = q[2], q3 = q[3];                      \
        ACC[0] += q0.x; ACC[1] += q0.y; ACC[2] += q0.z; ACC[3] += q0.w;         \
        ACC[4] += q1.x; ACC[5] += q1.y; ACC[6] += q1.z; ACC[7] += q1.w;         \
        ACC[8] += q2.x; ACC[9] += q2.y; ACC[10] += q2.z; ACC[11] += q2.w;       \
        ACC[12] += q3.x; ACC[13] += q3.y; ACC[14] += q3.z; ACC[15] += q3.w;     \
    }

// layer-1 aggregate + relu + layer-2 transform: hwsB = dinv * (h1 @ W2)
__global__ void __launch_bounds__(BLK) k_agg1(const float* __restrict__ hwsA,
                                              const int* __restrict__ offs,
                                              const int* __restrict__ degi,
                                              const int* __restrict__ srcs,
                                              const float* __restrict__ dinv,
                                              const float* __restrict__ b1,
                                              const float* __restrict__ W2,
                                              float* __restrict__ hwsB, int n) {
    __shared__ float w[256];
    __shared__ float bb[16];
    w[threadIdx.x] = W2[threadIdx.x];
    if (threadIdx.x < 16) bb[threadIdx.x] = b1[threadIdx.x];
    __syncthreads();
    int i = blockIdx.x * BLK + threadIdx.x;
    if (i >= n) return;
    float acc[16];
#pragma unroll
    for (int f = 0; f < 16; f++) acc[f] = 2.0f * hwsA[i * 16 + f];
    int beg = offs[i], end = beg + degi[i];
    for (int j = beg; j < end; j++) {
        int r = srcs[j];
        GATHER16(hwsA, r, acc);
    }
    float di = dinv[i];
    float h[16];
#pragma unroll
    for (int f = 0; f < 16; f++) {
        float v = di * acc[f] + bb[f];
        h[f] = v > 0.0f ? v : 0.0f;
    }
#pragma unroll
    for (int fo = 0; fo < 16; fo++) {
        float s = 0.0f;
#pragma unroll
        for (int f = 0; f < 16; f++) s += h[f] * w[f * 16 + fo];
        hwsB[i * 16 + fo] = di * s;
    }
}

// layer-2 aggregate + relu (-> h2), pool accumulation, layer-3 transform
__global__ void __launch_bounds__(BLK) k_agg2(const float* __restrict__ hwsB,
                                              const int* __restrict__ offs,
                                              const int* __restrict__ degi,
                                              const int* __restrict__ srcs,
                                              const float* __restrict__ dinv,
                                              const float* __restrict__ b2,
                                              const float* __restrict__ W3,
                                              float* __restrict__ hws3,
                                              float* __restrict__ pool, int n) {
    __shared__ float w3[16];
    __shared__ float bb[16];
    __shared__ float lp[16];
    if (threadIdx.x < 16) {
        w3[threadIdx.x] = W3[threadIdx.x];
        bb[threadIdx.x] = b2[threadIdx.x];
        lp[threadIdx.x] = 0.0f;
    }
    __syncthreads();
    int i = blockIdx.x * BLK + threadIdx.x;
    if (i < n) {
        float acc[16];
#pragma unroll
        for (int f = 0; f < 16; f++) acc[f] = 2.0f * hwsB[i * 16 + f];
        int beg = offs[i], end = beg + degi[i];
        for (int j = beg; j < end; j++) {
            int r = srcs[j];
            GATHER16(hwsB, r, acc);
        }
        float di = dinv[i];
        float hw3 = 0.0f;
#pragma unroll
        for (int f = 0; f < 16; f++) {
            float v = di * acc[f] + bb[f];
            float h = v > 0.0f ? v : 0.0f;
            hw3 += h * w3[f];
            atomicAdd(&lp[f], h);
        }
        hws3[i] = di * hw3;
    }
    __syncthreads();
    if (threadIdx.x < 16) atomicAdd(&pool[threadIdx.x], lp[threadIdx.x]);
}

// layer-3 aggregate -> logits c[n]; per-block max of masked logits
__global__ void __launch_bounds__(BLK) k_agg3(const float* __restrict__ hws3,
                                              const int* __restrict__ offs,
                                              const int* __restrict__ degi,
                                              const int* __restrict__ srcs,
                                              const float* __restrict__ dinv,
                                              const float* __restrict__ b3,
                                              const int* __restrict__ choices,
                                              float* __restrict__ cbuf,
                                              float* __restrict__ pmax, int n) {
    __shared__ float red[BLK];
    int i = blockIdx.x * BLK + threadIdx.x;
    float logit = -INFINITY;
    if (i < n) {
        float s = 2.0f * hws3[i];
        int beg = offs[i], end = beg + degi[i];
        for (int j = beg; j < end; j++) s += hws3[srcs[j]];
        float c = dinv[i] * s + b3[0];
        cbuf[i] = c;
        if (choices[i] != 0) logit = c;
    }
    red[threadIdx.x] = logit;
    __syncthreads();
    for (int d = BLK / 2; d > 0; d >>= 1) {
        if (threadIdx.x < d) red[threadIdx.x] = fmaxf(red[threadIdx.x], red[threadIdx.x + d]);
        __syncthreads();
    }
    if (threadIdx.x == 0) pmax[blockIdx.x] = red[0];
}

__global__ void k_redmax(const float* __restrict__ pmax, float* __restrict__ scal_m, int nblk) {
    __shared__ float red[BLK];
    float m = -INFINITY;
    for (int i = threadIdx.x; i < nblk; i += BLK) m = fmaxf(m, pmax[i]);
    red[threadIdx.x] = m;
    __syncthreads();
    for (int d = BLK / 2; d > 0; d >>= 1) {
        if (threadIdx.x < d) red[threadIdx.x] = fmaxf(red[threadIdx.x], red[threadIdx.x + d]);
        __syncthreads();
    }
    if (threadIdx.x == 0) scal_m[0] = red[0];
}

__global__ void __launch_bounds__(BLK) k_sumexp(const float* __restrict__ cbuf,
                                                const int* __restrict__ choices,
                                                const float* __restrict__ scal_m,
                                                float* __restrict__ Ssum, int n) {
    __shared__ float red[BLK];
    int i = blockIdx.x * BLK + threadIdx.x;
    float m = scal_m[0];
    float v = 0.0f;
    if (i < n && choices[i] != 0) v = expf(cbuf[i] - m);
    red[threadIdx.x] = v;
    __syncthreads();
    for (int d = BLK / 2; d > 0; d >>= 1) {
        if (threadIdx.x < d) red[threadIdx.x] += red[threadIdx.x + d];
        __syncthreads();
    }
    if (threadIdx.x == 0) atomicAdd(Ssum, red[0]);
}

__global__ void __launch_bounds__(BLK) k_final(const float* __restrict__ cbuf,
                                               const int* __restrict__ choices,
                                               const float* __restrict__ scal_m,
                                               const float* __restrict__ Ssum,
                                               const float* __restrict__ pool,
                                               const float* __restrict__ fcw,
                                               const float* __restrict__ fcb,
                                               float* __restrict__ out, int n) {
    int i = blockIdx.x * BLK + threadIdx.x;
    if (i < n) {
        float p = 0.0f;
        if (choices[i] != 0) {
            float m = scal_m[0], S = Ssum[0];
            p = expf(cbuf[i] - m) / S;
        }
        out[i] = p;
    }
    if (blockIdx.x == 0 && threadIdx.x == 0) {
        float invn = 1.0f / (float)n;
        float v = 0.0f;
#pragma unroll
        for (int f = 0; f < 16; f++) v += (pool[f] * invn) * fcw[f];
        out[n] = v + fcb[0];
    }
}

extern "C" void kernel_launch(void* const* d_in, const int* in_sizes, int n_in,
                              void* d_out, int out_size, void* d_ws, size_t ws_size,
                              hipStream_t stream) {
    const float* x       = (const float*)d_in[0];
    const int*   ei      = (const int*)d_in[1];
    const int*   choices = (const int*)d_in[2];
    const float* W1 = (const float*)d_in[3];
    const float* b1 = (const float*)d_in[4];
    const float* W2 = (const float*)d_in[5];
    const float* b2 = (const float*)d_in[6];
    const float* W3 = (const float*)d_in[7];
    const float* b3 = (const float*)d_in[8];
    const float* fcw = (const float*)d_in[9];
    const float* fcb = (const float*)d_in[10];
    float* out = (float*)d_out;

    int n = in_sizes[0] / 3;
    int E = in_sizes[1] / 2;
    const int* row = ei;
    const int* col = ei + E;

    int nblkN = (n + BLK - 1) / BLK;           // 391
    int nbuck = (n + (1 << BSH) - 1) >> BSH;   // 196 buckets of 512 nodes
    int nblkBin = (E + EB - 1) / EB;           // 391 binning blocks

    // workspace layout (16B aligned slices)
    char* ws = (char*)d_ws;
    size_t o = 0;
    auto alloc = [&](size_t bytes) { char* p = ws + o; o += (bytes + 15) & ~(size_t)15; return p; };
    int*   degi   = (int*)  alloc((size_t)n * 4);
    int*   offs   = (int*)  alloc((size_t)n * 4);
    float* dinv   = (float*)alloc((size_t)n * 4);
    float* hws3   = (float*)alloc((size_t)n * 4);
    float* cbuf   = (float*)alloc((size_t)n * 4);
    float* pmax   = (float*)alloc(4096);
    int*   bcnt   = (int*)  alloc(4096);
    int*   gcur   = (int*)  alloc(4096);
    int*   bbase  = (int*)  alloc(4096);
    float* scal   = (float*)alloc(256);   // [0]=S, [1..16]=pool, [17]=m
    float* Ssum   = scal + 0;
    float* pool   = scal + 1;
    float* scal_m = scal + 17;
    size_t hw_bytes = (size_t)n * 16 * 4 * 2;            // hwsA + hwsB
    size_t pk_bytes = (size_t)E * 4;                     // packed (aliases hwsA/B)
    char*  blob   = alloc(hw_bytes > pk_bytes ? hw_bytes : pk_bytes);
    float* hwsA   = (float*)blob;
    float* hwsB   = hwsA + (size_t)n * 16;
    int*   packed = (int*)blob;           // build phase only; dead before k_l1
    int*   srcs   = (int*)  alloc((size_t)E * 4);
    (void)ws_size;

    hipMemsetAsync(bcnt, 0, 1024, stream);
    hipMemsetAsync(scal, 0, 68, stream);   // S + pool[16]

    // ---- CSR build (no per-edge global atomics) ----
    k_bcount<<<nblkBin, BLK, 0, stream>>>(col, bcnt, E);
    k_bscan<<<1, 256, 0, stream>>>(bcnt, gcur, bbase, nbuck);
    k_bin<<<nblkBin, BINTH, 0, stream>>>(row, col, gcur, packed, E);
    k_place<<<nbuck, BLK, 0, stream>>>(packed, bbase, bcnt, degi, offs, dinv, srcs, n);

    // ---- GCN layers ----
    k_l1<<<nblkN, BLK, 0, stream>>>(x, W1, dinv, hwsA, n);
    k_agg1<<<nblkN, BLK, 0, stream>>>(hwsA, offs, degi, srcs, dinv, b1, W2, hwsB, n);
    k_agg2<<<nblkN, BLK, 0, stream>>>(hwsB, offs, degi, srcs, dinv, b2, W3, hws3, pool, n);
    k_agg3<<<nblkN, BLK, 0, stream>>>(hws3, offs, degi, srcs, dinv, b3, choices, cbuf, pmax, n);

    // ---- softmax + value head ----
    k_redmax<<<1, BLK, 0, stream>>>(pmax, scal_m, nblkN);
    k_sumexp<<<nblkN, BLK, 0, stream>>>(cbuf, choices, scal_m, Ssum, n);
    k_final<<<nblkN, BLK, 0, stream>>>(cbuf, choices, scal_m, Ssum, pool, fcw, fcb, out, n);
}

// Round 4
// 331.252 us; speedup vs baseline: 2.1651x; 1.1772x over previous
//
#include <hip/hip_runtime.h>
#include <math.h>

#define BLK 256

// ---------------------------------------------------------------------------
// GCNPolicyNetwork: 3-layer improved-GCN + masked softmax + mean-pool value.
// Round 4: agg kernels were latency-bound (Occupancy 14%, VALUBusy 9%,
// 1.3 TB/s effective). Now 4 lanes per node: each lane gathers one float4 of
// the node's 16 features (4 lanes hit the same 64B line -> 1 coalesced
// transaction/edge), 4x thread count (-> ~75% occupancy), x2 unrolled gather
// with dual accumulators. Layer matmul via padded LDS tile; w3-dot & pool via
// shfl_xor; agg3 splits its edge list across the 4 lanes.
// ---------------------------------------------------------------------------

#define BSH 9                    // 512 nodes per bucket
#define EB 8192                  // edges per binning block
#define BINTH 512                // k_bin block size

// per-block LDS histogram of bucket ids, flush with <=196 global atomics
__global__ void __launch_bounds__(BLK) k_bcount(const int* __restrict__ col,
                                                int* __restrict__ bcnt, int E) {
    __shared__ int hist[256];
    int tid = threadIdx.x;
    int base = blockIdx.x * EB;
    int cnt = min(EB, E - base);
    hist[tid] = 0;
    __syncthreads();
    for (int j = tid; j < cnt; j += BLK)
        atomicAdd(&hist[col[base + j] >> BSH], 1);
    __syncthreads();
    if (hist[tid] > 0) atomicAdd(&bcnt[tid], hist[tid]);
}

// single-block exclusive scan of bucket counts -> gcur (mutable) + bbase (kept)
__global__ void k_bscan(const int* __restrict__ bcnt, int* __restrict__ gcur,
                        int* __restrict__ bbase, int nbuck) {
    __shared__ int s[256];
    int tid = threadIdx.x;
    int v = (tid < nbuck) ? bcnt[tid] : 0;
    s[tid] = v;
    __syncthreads();
    for (int d = 1; d < 256; d <<= 1) {
        int t = (tid >= d) ? s[tid - d] : 0;
        __syncthreads();
        if (tid >= d) s[tid] += t;
        __syncthreads();
    }
    int ex = s[tid] - v;
    gcur[tid] = ex;
    bbase[tid] = ex;
}

// pass 1: LDS multisplit of edges into buckets, coalesced flush to packed[]
__global__ void __launch_bounds__(BINTH) k_bin(const int* __restrict__ row,
                                               const int* __restrict__ col,
                                               int* __restrict__ gcur,
                                               int* __restrict__ packed, int E) {
    __shared__ int stage[EB];            // packed edges, bucket-sorted locally
    __shared__ unsigned char sbuk[EB];   // bucket id per staged slot
    __shared__ int hist[256];
    __shared__ int lscan[256];
    __shared__ int cur[256];
    __shared__ int gbase[256];
    int tid = threadIdx.x;
    int base = blockIdx.x * EB;
    int cnt = min(EB, E - base);

    if (tid < 256) hist[tid] = 0;
    __syncthreads();
    for (int j = tid; j < cnt; j += BINTH) {
        int c = col[base + j];
        atomicAdd(&hist[c >> BSH], 1);
    }
    __syncthreads();
    if (tid < 256) lscan[tid] = hist[tid];
    __syncthreads();
    for (int d = 1; d < 256; d <<= 1) {
        int t = 0;
        if (tid < 256 && tid >= d) t = lscan[tid - d];
        __syncthreads();
        if (tid < 256 && tid >= d) lscan[tid] += t;
        __syncthreads();
    }
    if (tid < 256) {
        int ex = lscan[tid] - hist[tid];
        lscan[tid] = ex;
        cur[tid] = ex;
    }
    __syncthreads();
    for (int j = tid; j < cnt; j += BINTH) {
        int c = col[base + j];
        int r = row[base + j];
        int b = c >> BSH;
        int p = atomicAdd(&cur[b], 1);
        stage[p] = (r << BSH) | (c & ((1 << BSH) - 1));
        sbuk[p] = (unsigned char)b;
    }
    __syncthreads();
    if (tid < 256 && hist[tid] > 0) gbase[tid] = atomicAdd(&gcur[tid], hist[tid]);
    __syncthreads();
    for (int j = tid; j < cnt; j += BINTH) {
        int b = sbuk[j];
        int pos = gbase[b] + (j - lscan[b]);
        packed[pos] = stage[j];
    }
}

// pass 2: per-bucket degree count + scan (-> degi/offs/dinv) + fine placement
__global__ void __launch_bounds__(BLK) k_place(const int* __restrict__ packed,
                                               const int* __restrict__ bbase,
                                               const int* __restrict__ bcnt,
                                               int* __restrict__ degi,
                                               int* __restrict__ offs,
                                               float* __restrict__ dinv,
                                               int* __restrict__ srcs, int n) {
    __shared__ int cnt[1 << BSH];
    __shared__ int lcur[1 << BSH];
    __shared__ int ssum[BLK];
    int tid = threadIdx.x;
    int b = blockIdx.x;
    int nb0 = b << BSH;
    for (int t = tid; t < (1 << BSH); t += BLK) cnt[t] = 0;
    __syncthreads();
    int pbeg = bbase[b];
    int pend = pbeg + bcnt[b];
    for (int j = pbeg + tid; j < pend; j += BLK)
        atomicAdd(&cnt[packed[j] & ((1 << BSH) - 1)], 1);
    __syncthreads();
    int c0 = cnt[2 * tid], c1 = cnt[2 * tid + 1];
    int pair = c0 + c1;
    ssum[tid] = pair;
    __syncthreads();
    for (int d = 1; d < BLK; d <<= 1) {
        int t = (tid >= d) ? ssum[tid - d] : 0;
        __syncthreads();
        if (tid >= d) ssum[tid] += t;
        __syncthreads();
    }
    int ex = ssum[tid] - pair;
    lcur[2 * tid] = ex;
    lcur[2 * tid + 1] = ex + c0;
    int node0 = nb0 + 2 * tid;
    if (node0 < n) {
        degi[node0] = c0;
        offs[node0] = pbeg + ex;
        dinv[node0] = rsqrtf((float)c0 + 2.0f);
    }
    if (node0 + 1 < n) {
        degi[node0 + 1] = c1;
        offs[node0 + 1] = pbeg + ex + c0;
        dinv[node0 + 1] = rsqrtf((float)c1 + 2.0f);
    }
    __syncthreads();
    for (int j = pbeg + tid; j < pend; j += BLK) {
        int v = packed[j];
        int li = v & ((1 << BSH) - 1);
        int r = v >> BSH;
        int slot = atomicAdd(&lcur[li], 1);
        srcs[pbeg + slot] = r;
    }
}

// layer-1 transform: hwsA = dinv * (x @ W1)   (x is N x 3)
__global__ void __launch_bounds__(BLK) k_l1(const float* __restrict__ x,
                                            const float* __restrict__ W1,
                                            const float* __restrict__ dinv,
                                            float* __restrict__ hwsA, int n) {
    __shared__ float w[48];
    if (threadIdx.x < 48) w[threadIdx.x] = W1[threadIdx.x];
    __syncthreads();
    int i = blockIdx.x * BLK + threadIdx.x;
    if (i >= n) return;
    float x0 = x[i * 3 + 0], x1 = x[i * 3 + 1], x2 = x[i * 3 + 2];
    float di = dinv[i];
#pragma unroll
    for (int f = 0; f < 16; f++) {
        float hw = x0 * w[f] + x1 * w[16 + f] + x2 * w[32 + f];
        hwsA[i * 16 + f] = di * hw;
    }
}

// 4 lanes per node: lane sub handles features [sub*4, sub*4+4).
// Gather loop: x2 unrolled, dual accumulators; 4 lanes hit one 64B line.
#define GATHER4(HWS)                                                            \
    float4 acc = make_float4(0.f, 0.f, 0.f, 0.f);                               \
    {                                                                           \
        float4 acc2 = make_float4(0.f, 0.f, 0.f, 0.f);                          \
        const float4* sp = (const float4*)(HWS + ((size_t)i << 4)) + sub;       \
        float4 s0 = *sp;                                                        \
        acc.x = 2.f * s0.x; acc.y = 2.f * s0.y;                                 \
        acc.z = 2.f * s0.z; acc.w = 2.f * s0.w;                                 \
        int beg = offs[i], end = beg + degi[i];                                 \
        int j = beg;                                                            \
        for (; j + 1 < end; j += 2) {                                           \
            int r0 = srcs[j], r1 = srcs[j + 1];                                 \
            float4 q0 = *((const float4*)(HWS + ((size_t)r0 << 4)) + sub);      \
            float4 q1 = *((const float4*)(HWS + ((size_t)r1 << 4)) + sub);      \
            acc.x += q0.x; acc.y += q0.y; acc.z += q0.z; acc.w += q0.w;         \
            acc2.x += q1.x; acc2.y += q1.y; acc2.z += q1.z; acc2.w += q1.w;     \
        }                                                                       \
        if (j < end) {                                                          \
            int r0 = srcs[j];                                                   \
            float4 q0 = *((const float4*)(HWS + ((size_t)r0 << 4)) + sub);      \
            acc.x += q0.x; acc.y += q0.y; acc.z += q0.z; acc.w += q0.w;         \
        }                                                                       \
        acc.x += acc2.x; acc.y += acc2.y; acc.z += acc2.z; acc.w += acc2.w;     \
    }

// layer-1 aggregate + relu + layer-2 transform: hwsB = dinv * (h1 @ W2)
__global__ void __launch_bounds__(BLK) k_agg1(const float* __restrict__ hwsA,
                                              const int* __restrict__ offs,
                                              const int* __restrict__ degi,
                                              const int* __restrict__ srcs,
                                              const float* __restrict__ dinv,
                                              const float* __restrict__ b1,
                                              const float* __restrict__ W2,
                                              float* __restrict__ hwsB, int n) {
    __shared__ float w[256];
    __shared__ float bb[16];
    __shared__ float hbuf[64][17];           // +1 pad: conflict-free
    int tid = threadIdx.x;
    w[tid] = W2[tid];
    if (tid < 16) bb[tid] = b1[tid];
    __syncthreads();
    int nl = tid >> 2, sub = tid & 3;
    int i = blockIdx.x * 64 + nl;
    bool act = (i < n);
    float di = 0.f;
    float4 h = make_float4(0.f, 0.f, 0.f, 0.f);
    if (act) {
        di = dinv[i];
        GATHER4(hwsA);
        h.x = fmaxf(di * acc.x + bb[sub * 4 + 0], 0.f);
        h.y = fmaxf(di * acc.y + bb[sub * 4 + 1], 0.f);
        h.z = fmaxf(di * acc.z + bb[sub * 4 + 2], 0.f);
        h.w = fmaxf(di * acc.w + bb[sub * 4 + 3], 0.f);
    }
    hbuf[nl][sub * 4 + 0] = h.x;
    hbuf[nl][sub * 4 + 1] = h.y;
    hbuf[nl][sub * 4 + 2] = h.z;
    hbuf[nl][sub * 4 + 3] = h.w;
    __syncthreads();
    if (act) {
        const float* hn = hbuf[nl];
        float s0 = 0.f, s1 = 0.f, s2 = 0.f, s3 = 0.f;
#pragma unroll
        for (int f = 0; f < 16; f++) {
            float hv = hn[f];
            const float4 wq = *(const float4*)&w[f * 16 + sub * 4];
            s0 += hv * wq.x; s1 += hv * wq.y; s2 += hv * wq.z; s3 += hv * wq.w;
        }
        float4 o = make_float4(di * s0, di * s1, di * s2, di * s3);
        *((float4*)(hwsB + ((size_t)i << 4)) + sub) = o;
    }
}

// layer-2 aggregate + relu (-> h2), pool accumulation, layer-3 transform
__global__ void __launch_bounds__(BLK) k_agg2(const float* __restrict__ hwsB,
                                              const int* __restrict__ offs,
                                              const int* __restrict__ degi,
                                              const int* __restrict__ srcs,
                                              const float* __restrict__ dinv,
                                              const float* __restrict__ b2,
                                              const float* __restrict__ W3,
                                              float* __restrict__ hws3,
                                              float* __restrict__ pool, int n) {
    __shared__ float w3[16];
    __shared__ float bb[16];
    __shared__ float lp[16];
    int tid = threadIdx.x;
    if (tid < 16) { w3[tid] = W3[tid]; bb[tid] = b2[tid]; lp[tid] = 0.f; }
    __syncthreads();
    int nl = tid >> 2, sub = tid & 3;
    int i = blockIdx.x * 64 + nl;
    bool act = (i < n);
    float di = 0.f;
    float4 h = make_float4(0.f, 0.f, 0.f, 0.f);
    if (act) {
        di = dinv[i];
        GATHER4(hwsB);
        h.x = fmaxf(di * acc.x + bb[sub * 4 + 0], 0.f);
        h.y = fmaxf(di * acc.y + bb[sub * 4 + 1], 0.f);
        h.z = fmaxf(di * acc.z + bb[sub * 4 + 2], 0.f);
        h.w = fmaxf(di * acc.w + bb[sub * 4 + 3], 0.f);
    }
    // hw3 = h . w3 (partial over this lane's 4 features, reduce across 4 lanes)
    float p = h.x * w3[sub * 4 + 0] + h.y * w3[sub * 4 + 1]
            + h.z * w3[sub * 4 + 2] + h.w * w3[sub * 4 + 3];
    p += __shfl_xor(p, 1);
    p += __shfl_xor(p, 2);
    if (act && sub == 0) hws3[i] = di * p;
    // pool: reduce h over the wave's 16 nodes (lanes stride 4 share features)
    float4 hp = h;
#pragma unroll
    for (int m = 4; m < 64; m <<= 1) {
        hp.x += __shfl_xor(hp.x, m);
        hp.y += __shfl_xor(hp.y, m);
        hp.z += __shfl_xor(hp.z, m);
        hp.w += __shfl_xor(hp.w, m);
    }
    if ((tid & 63) < 4) {                    // lane==sub holds wave sum
        atomicAdd(&lp[sub * 4 + 0], hp.x);
        atomicAdd(&lp[sub * 4 + 1], hp.y);
        atomicAdd(&lp[sub * 4 + 2], hp.z);
        atomicAdd(&lp[sub * 4 + 3], hp.w);
    }
    __syncthreads();
    if (tid < 16) atomicAdd(&pool[tid], lp[tid]);
}

// layer-3 aggregate -> logits c[n]; per-block max of masked logits
__global__ void __launch_bounds__(BLK) k_agg3(const float* __restrict__ hws3,
                                              const int* __restrict__ offs,
                                              const int* __restrict__ degi,
                                              const int* __restrict__ srcs,
                                              const float* __restrict__ dinv,
                                              const float* __restrict__ b3,
                                              const int* __restrict__ choices,
                                              float* __restrict__ cbuf,
                                              float* __restrict__ pmax, int n) {
    __shared__ float red[BLK];
    int tid = threadIdx.x;
    int nl = tid >> 2, sub = tid & 3;
    int i = blockIdx.x * 64 + nl;
    bool act = (i < n);
    float s = 0.f;
    if (act) {
        int beg = offs[i], end = beg + degi[i];
        for (int j = beg + sub; j < end; j += 4) s += hws3[srcs[j]];
    }
    s += __shfl_xor(s, 1);
    s += __shfl_xor(s, 2);
    float logit = -INFINITY;
    if (act && sub == 0) {
        float c = dinv[i] * (s + 2.f * hws3[i]) + b3[0];
        cbuf[i] = c;
        if (choices[i] != 0) logit = c;
    }
    red[tid] = logit;
    __syncthreads();
    for (int d = BLK / 2; d > 0; d >>= 1) {
        if (tid < d) red[tid] = fmaxf(red[tid], red[tid + d]);
        __syncthreads();
    }
    if (tid == 0) pmax[blockIdx.x] = red[0];
}

__global__ void k_redmax(const float* __restrict__ pmax, float* __restrict__ scal_m, int nblk) {
    __shared__ float red[BLK];
    float m = -INFINITY;
    for (int i = threadIdx.x; i < nblk; i += BLK) m = fmaxf(m, pmax[i]);
    red[threadIdx.x] = m;
    __syncthreads();
    for (int d = BLK / 2; d > 0; d >>= 1) {
        if (threadIdx.x < d) red[threadIdx.x] = fmaxf(red[threadIdx.x], red[threadIdx.x + d]);
        __syncthreads();
    }
    if (threadIdx.x == 0) scal_m[0] = red[0];
}

__global__ void __launch_bounds__(BLK) k_sumexp(const float* __restrict__ cbuf,
                                                const int* __restrict__ choices,
                                                const float* __restrict__ scal_m,
                                                float* __restrict__ Ssum, int n) {
    __shared__ float red[BLK];
    int i = blockIdx.x * BLK + threadIdx.x;
    float m = scal_m[0];
    float v = 0.0f;
    if (i < n && choices[i] != 0) v = expf(cbuf[i] - m);
    red[threadIdx.x] = v;
    __syncthreads();
    for (int d = BLK / 2; d > 0; d >>= 1) {
        if (threadIdx.x < d) red[threadIdx.x] += red[threadIdx.x + d];
        __syncthreads();
    }
    if (threadIdx.x == 0) atomicAdd(Ssum, red[0]);
}

__global__ void __launch_bounds__(BLK) k_final(const float* __restrict__ cbuf,
                                               const int* __restrict__ choices,
                                               const float* __restrict__ scal_m,
                                               const float* __restrict__ Ssum,
                                               const float* __restrict__ pool,
                                               const float* __restrict__ fcw,
                                               const float* __restrict__ fcb,
                                               float* __restrict__ out, int n) {
    int i = blockIdx.x * BLK + threadIdx.x;
    if (i < n) {
        float p = 0.0f;
        if (choices[i] != 0) {
            float m = scal_m[0], S = Ssum[0];
            p = expf(cbuf[i] - m) / S;
        }
        out[i] = p;
    }
    if (blockIdx.x == 0 && threadIdx.x == 0) {
        float invn = 1.0f / (float)n;
        float v = 0.0f;
#pragma unroll
        for (int f = 0; f < 16; f++) v += (pool[f] * invn) * fcw[f];
        out[n] = v + fcb[0];
    }
}

extern "C" void kernel_launch(void* const* d_in, const int* in_sizes, int n_in,
                              void* d_out, int out_size, void* d_ws, size_t ws_size,
                              hipStream_t stream) {
    const float* x       = (const float*)d_in[0];
    const int*   ei      = (const int*)d_in[1];
    const int*   choices = (const int*)d_in[2];
    const float* W1 = (const float*)d_in[3];
    const float* b1 = (const float*)d_in[4];
    const float* W2 = (const float*)d_in[5];
    const float* b2 = (const float*)d_in[6];
    const float* W3 = (const float*)d_in[7];
    const float* b3 = (const float*)d_in[8];
    const float* fcw = (const float*)d_in[9];
    const float* fcb = (const float*)d_in[10];
    float* out = (float*)d_out;

    int n = in_sizes[0] / 3;
    int E = in_sizes[1] / 2;
    const int* row = ei;
    const int* col = ei + E;

    int nblkN = (n + BLK - 1) / BLK;           // 391
    int nblk64 = (n + 63) / 64;                // 1563  (4 lanes/node kernels)
    int nbuck = (n + (1 << BSH) - 1) >> BSH;   // 196 buckets of 512 nodes
    int nblkBin = (E + EB - 1) / EB;           // 391 binning blocks

    // workspace layout (16B aligned slices)
    char* ws = (char*)d_ws;
    size_t o = 0;
    auto alloc = [&](size_t bytes) { char* p = ws + o; o += (bytes + 15) & ~(size_t)15; return p; };
    int*   degi   = (int*)  alloc((size_t)n * 4);
    int*   offs   = (int*)  alloc((size_t)n * 4);
    float* dinv   = (float*)alloc((size_t)n * 4);
    float* hws3   = (float*)alloc((size_t)n * 4);
    float* cbuf   = (float*)alloc((size_t)n * 4);
    float* pmax   = (float*)alloc(8192);       // >= nblk64 floats
    int*   bcnt   = (int*)  alloc(4096);
    int*   gcur   = (int*)  alloc(4096);
    int*   bbase  = (int*)  alloc(4096);
    float* scal   = (float*)alloc(256);   // [0]=S, [1..16]=pool, [17]=m
    float* Ssum   = scal + 0;
    float* pool   = scal + 1;
    float* scal_m = scal + 17;
    size_t hw_bytes = (size_t)n * 16 * 4 * 2;            // hwsA + hwsB
    size_t pk_bytes = (size_t)E * 4;                     // packed (aliases hwsA/B)
    char*  blob   = alloc(hw_bytes > pk_bytes ? hw_bytes : pk_bytes);
    float* hwsA   = (float*)blob;
    float* hwsB   = hwsA + (size_t)n * 16;
    int*   packed = (int*)blob;           // build phase only; dead before k_l1
    int*   srcs   = (int*)  alloc((size_t)E * 4);
    (void)ws_size;

    hipMemsetAsync(bcnt, 0, 1024, stream);
    hipMemsetAsync(scal, 0, 68, stream);   // S + pool[16]

    // ---- CSR build (no per-edge global atomics) ----
    k_bcount<<<nblkBin, BLK, 0, stream>>>(col, bcnt, E);
    k_bscan<<<1, 256, 0, stream>>>(bcnt, gcur, bbase, nbuck);
    k_bin<<<nblkBin, BINTH, 0, stream>>>(row, col, gcur, packed, E);
    k_place<<<nbuck, BLK, 0, stream>>>(packed, bbase, bcnt, degi, offs, dinv, srcs, n);

    // ---- GCN layers (4 lanes per node) ----
    k_l1<<<nblkN, BLK, 0, stream>>>(x, W1, dinv, hwsA, n);
    k_agg1<<<nblk64, BLK, 0, stream>>>(hwsA, offs, degi, srcs, dinv, b1, W2, hwsB, n);
    k_agg2<<<nblk64, BLK, 0, stream>>>(hwsB, offs, degi, srcs, dinv, b2, W3, hws3, pool, n);
    k_agg3<<<nblk64, BLK, 0, stream>>>(hws3, offs, degi, srcs, dinv, b3, choices, cbuf, pmax, n);

    // ---- softmax + value head ----
    k_redmax<<<1, BLK, 0, stream>>>(pmax, scal_m, nblk64);
    k_sumexp<<<nblkN, BLK, 0, stream>>>(cbuf, choices, scal_m, Ssum, n);
    k_final<<<nblkN, BLK, 0, stream>>>(cbuf, choices, scal_m, Ssum, pool, fcw, fcb, out, n);
}

// Round 5
// 292.711 us; speedup vs baseline: 2.4502x; 1.1317x over previous
//
#include <hip/hip_runtime.h>
#include <hip/hip_fp16.h>
#include <math.h>

#define BLK 256

// ---------------------------------------------------------------------------
// GCNPolicyNetwork: 3-layer improved-GCN + masked softmax + mean-pool value.
// Round 5: agg kernels were L2-capacity-bound: hws fp32 = 6.4 MB > 4 MB
// per-XCD L2 -> 149 MB FETCH_SIZE (L2 thrash, every gather pays L3 latency).
// hws now stored fp16 (3.2 MB -> fits in each XCD's L2). Gather payload is
// 8 B/lane (4 lanes cover one 32 B segment/edge). All math stays fp32; only
// the staged per-node features are rounded. Gather unrolled x4.
// ---------------------------------------------------------------------------

#define BSH 9                    // 512 nodes per bucket
#define EB 8192                  // edges per binning block
#define BINTH 512                // k_bin block size

// ---- fp16 payload helpers (4 features per lane = 8 B) ----
__device__ inline float4 load_h4(const __half* base, int node, int sub) {
    const uint2* p = reinterpret_cast<const uint2*>(base + ((size_t)node << 4)) + sub;
    uint2 u = *p;
    union { unsigned u; __half2 h; } a, b;
    a.u = u.x; b.u = u.y;
    float2 fa = __half22float2(a.h), fb = __half22float2(b.h);
    return make_float4(fa.x, fa.y, fb.x, fb.y);
}

__device__ inline void store_h4(__half* base, int node, int sub, float4 v) {
    union { unsigned u; __half2 h; } a, b;
    a.h = __floats2half2_rn(v.x, v.y);
    b.h = __floats2half2_rn(v.z, v.w);
    uint2 u; u.x = a.u; u.y = b.u;
    *(reinterpret_cast<uint2*>(base + ((size_t)node << 4)) + sub) = u;
}

// per-block LDS histogram of bucket ids, flush with <=196 global atomics
__global__ void __launch_bounds__(BLK) k_bcount(const int* __restrict__ col,
                                                int* __restrict__ bcnt, int E) {
    __shared__ int hist[256];
    int tid = threadIdx.x;
    int base = blockIdx.x * EB;
    int cnt = min(EB, E - base);
    hist[tid] = 0;
    __syncthreads();
    for (int j = tid; j < cnt; j += BLK)
        atomicAdd(&hist[col[base + j] >> BSH], 1);
    __syncthreads();
    if (hist[tid] > 0) atomicAdd(&bcnt[tid], hist[tid]);
}

// single-block exclusive scan of bucket counts -> gcur (mutable) + bbase (kept)
__global__ void k_bscan(const int* __restrict__ bcnt, int* __restrict__ gcur,
                        int* __restrict__ bbase, int nbuck) {
    __shared__ int s[256];
    int tid = threadIdx.x;
    int v = (tid < nbuck) ? bcnt[tid] : 0;
    s[tid] = v;
    __syncthreads();
    for (int d = 1; d < 256; d <<= 1) {
        int t = (tid >= d) ? s[tid - d] : 0;
        __syncthreads();
        if (tid >= d) s[tid] += t;
        __syncthreads();
    }
    int ex = s[tid] - v;
    gcur[tid] = ex;
    bbase[tid] = ex;
}

// pass 1: LDS multisplit of edges into buckets, coalesced flush to packed[]
__global__ void __launch_bounds__(BINTH) k_bin(const int* __restrict__ row,
                                               const int* __restrict__ col,
                                               int* __restrict__ gcur,
                                               int* __restrict__ packed, int E) {
    __shared__ int stage[EB];            // packed edges, bucket-sorted locally
    __shared__ unsigned char sbuk[EB];   // bucket id per staged slot
    __shared__ int hist[256];
    __shared__ int lscan[256];
    __shared__ int cur[256];
    __shared__ int gbase[256];
    int tid = threadIdx.x;
    int base = blockIdx.x * EB;
    int cnt = min(EB, E - base);

    if (tid < 256) hist[tid] = 0;
    __syncthreads();
    for (int j = tid; j < cnt; j += BINTH) {
        int c = col[base + j];
        atomicAdd(&hist[c >> BSH], 1);
    }
    __syncthreads();
    if (tid < 256) lscan[tid] = hist[tid];
    __syncthreads();
    for (int d = 1; d < 256; d <<= 1) {
        int t = 0;
        if (tid < 256 && tid >= d) t = lscan[tid - d];
        __syncthreads();
        if (tid < 256 && tid >= d) lscan[tid] += t;
        __syncthreads();
    }
    if (tid < 256) {
        int ex = lscan[tid] - hist[tid];
        lscan[tid] = ex;
        cur[tid] = ex;
    }
    __syncthreads();
    for (int j = tid; j < cnt; j += BINTH) {
        int c = col[base + j];
        int r = row[base + j];
        int b = c >> BSH;
        int p = atomicAdd(&cur[b], 1);
        stage[p] = (r << BSH) | (c & ((1 << BSH) - 1));
        sbuk[p] = (unsigned char)b;
    }
    __syncthreads();
    if (tid < 256 && hist[tid] > 0) gbase[tid] = atomicAdd(&gcur[tid], hist[tid]);
    __syncthreads();
    for (int j = tid; j < cnt; j += BINTH) {
        int b = sbuk[j];
        int pos = gbase[b] + (j - lscan[b]);
        packed[pos] = stage[j];
    }
}

// pass 2: per-bucket degree count + scan (-> degi/offs/dinv) + fine placement
__global__ void __launch_bounds__(BLK) k_place(const int* __restrict__ packed,
                                               const int* __restrict__ bbase,
                                               const int* __restrict__ bcnt,
                                               int* __restrict__ degi,
                                               int* __restrict__ offs,
                                               float* __restrict__ dinv,
                                               int* __restrict__ srcs, int n) {
    __shared__ int cnt[1 << BSH];
    __shared__ int lcur[1 << BSH];
    __shared__ int ssum[BLK];
    int tid = threadIdx.x;
    int b = blockIdx.x;
    int nb0 = b << BSH;
    for (int t = tid; t < (1 << BSH); t += BLK) cnt[t] = 0;
    __syncthreads();
    int pbeg = bbase[b];
    int pend = pbeg + bcnt[b];
    for (int j = pbeg + tid; j < pend; j += BLK)
        atomicAdd(&cnt[packed[j] & ((1 << BSH) - 1)], 1);
    __syncthreads();
    int c0 = cnt[2 * tid], c1 = cnt[2 * tid + 1];
    int pair = c0 + c1;
    ssum[tid] = pair;
    __syncthreads();
    for (int d = 1; d < BLK; d <<= 1) {
        int t = (tid >= d) ? ssum[tid - d] : 0;
        __syncthreads();
        if (tid >= d) ssum[tid] += t;
        __syncthreads();
    }
    int ex = ssum[tid] - pair;
    lcur[2 * tid] = ex;
    lcur[2 * tid + 1] = ex + c0;
    int node0 = nb0 + 2 * tid;
    if (node0 < n) {
        degi[node0] = c0;
        offs[node0] = pbeg + ex;
        dinv[node0] = rsqrtf((float)c0 + 2.0f);
    }
    if (node0 + 1 < n) {
        degi[node0 + 1] = c1;
        offs[node0 + 1] = pbeg + ex + c0;
        dinv[node0 + 1] = rsqrtf((float)c1 + 2.0f);
    }
    __syncthreads();
    for (int j = pbeg + tid; j < pend; j += BLK) {
        int v = packed[j];
        int li = v & ((1 << BSH) - 1);
        int r = v >> BSH;
        int slot = atomicAdd(&lcur[li], 1);
        srcs[pbeg + slot] = r;
    }
}

// layer-1 transform: hwsA = dinv * (x @ W1)   (x is N x 3), fp16 store
__global__ void __launch_bounds__(BLK) k_l1(const float* __restrict__ x,
                                            const float* __restrict__ W1,
                                            const float* __restrict__ dinv,
                                            __half* __restrict__ hwsA, int n) {
    __shared__ float w[48];
    if (threadIdx.x < 48) w[threadIdx.x] = W1[threadIdx.x];
    __syncthreads();
    int i = blockIdx.x * BLK + threadIdx.x;
    if (i >= n) return;
    float x0 = x[i * 3 + 0], x1 = x[i * 3 + 1], x2 = x[i * 3 + 2];
    float di = dinv[i];
#pragma unroll
    for (int sub = 0; sub < 4; sub++) {
        float4 o;
        float* op = &o.x;
#pragma unroll
        for (int k = 0; k < 4; k++) {
            int f = sub * 4 + k;
            op[k] = di * (x0 * w[f] + x1 * w[16 + f] + x2 * w[32 + f]);
        }
        store_h4(hwsA, i, sub, o);
    }
}

// 4 lanes per node: lane sub handles features [sub*4, sub*4+4).
// fp16 payload gather, x4 unrolled, 4 fp32 accumulators.
#define GATHER4H(HWS)                                                           \
    float4 acc;                                                                 \
    {                                                                           \
        float4 s0 = load_h4(HWS, i, sub);                                       \
        acc = make_float4(2.f * s0.x, 2.f * s0.y, 2.f * s0.z, 2.f * s0.w);      \
        float4 a1 = make_float4(0.f, 0.f, 0.f, 0.f);                            \
        float4 a2 = a1, a3 = a1;                                                \
        int beg = offs[i], end = beg + degi[i];                                 \
        int j = beg;                                                            \
        for (; j + 3 < end; j += 4) {                                           \
            int r0 = srcs[j], r1 = srcs[j + 1], r2 = srcs[j + 2], r3 = srcs[j + 3]; \
            float4 q0 = load_h4(HWS, r0, sub);                                  \
            float4 q1 = load_h4(HWS, r1, sub);                                  \
            float4 q2 = load_h4(HWS, r2, sub);                                  \
            float4 q3 = load_h4(HWS, r3, sub);                                  \
            acc.x += q0.x; acc.y += q0.y; acc.z += q0.z; acc.w += q0.w;         \
            a1.x += q1.x; a1.y += q1.y; a1.z += q1.z; a1.w += q1.w;             \
            a2.x += q2.x; a2.y += q2.y; a2.z += q2.z; a2.w += q2.w;             \
            a3.x += q3.x; a3.y += q3.y; a3.z += q3.z; a3.w += q3.w;             \
        }                                                                       \
        for (; j < end; j++) {                                                  \
            int r0 = srcs[j];                                                   \
            float4 q0 = load_h4(HWS, r0, sub);                                  \
            acc.x += q0.x; acc.y += q0.y; acc.z += q0.z; acc.w += q0.w;         \
        }                                                                       \
        acc.x += a1.x + a2.x + a3.x;                                            \
        acc.y += a1.y + a2.y + a3.y;                                            \
        acc.z += a1.z + a2.z + a3.z;                                            \
        acc.w += a1.w + a2.w + a3.w;                                            \
    }

// layer-1 aggregate + relu + layer-2 transform: hwsB = dinv * (h1 @ W2)
__global__ void __launch_bounds__(BLK) k_agg1(const __half* __restrict__ hwsA,
                                              const int* __restrict__ offs,
                                              const int* __restrict__ degi,
                                              const int* __restrict__ srcs,
                                              const float* __restrict__ dinv,
                                              const float* __restrict__ b1,
                                              const float* __restrict__ W2,
                                              __half* __restrict__ hwsB, int n) {
    __shared__ float w[256];
    __shared__ float bb[16];
    __shared__ float hbuf[64][17];           // +1 pad: conflict-free
    int tid = threadIdx.x;
    w[tid] = W2[tid];
    if (tid < 16) bb[tid] = b1[tid];
    __syncthreads();
    int nl = tid >> 2, sub = tid & 3;
    int i = blockIdx.x * 64 + nl;
    bool act = (i < n);
    float di = 0.f;
    float4 h = make_float4(0.f, 0.f, 0.f, 0.f);
    if (act) {
        di = dinv[i];
        GATHER4H(hwsA);
        h.x = fmaxf(di * acc.x + bb[sub * 4 + 0], 0.f);
        h.y = fmaxf(di * acc.y + bb[sub * 4 + 1], 0.f);
        h.z = fmaxf(di * acc.z + bb[sub * 4 + 2], 0.f);
        h.w = fmaxf(di * acc.w + bb[sub * 4 + 3], 0.f);
    }
    hbuf[nl][sub * 4 + 0] = h.x;
    hbuf[nl][sub * 4 + 1] = h.y;
    hbuf[nl][sub * 4 + 2] = h.z;
    hbuf[nl][sub * 4 + 3] = h.w;
    __syncthreads();
    if (act) {
        const float* hn = hbuf[nl];
        float s0 = 0.f, s1 = 0.f, s2 = 0.f, s3 = 0.f;
#pragma unroll
        for (int f = 0; f < 16; f++) {
            float hv = hn[f];
            const float4 wq = *(const float4*)&w[f * 16 + sub * 4];
            s0 += hv * wq.x; s1 += hv * wq.y; s2 += hv * wq.z; s3 += hv * wq.w;
        }
        store_h4(hwsB, i, sub, make_float4(di * s0, di * s1, di * s2, di * s3));
    }
}

// layer-2 aggregate + relu (-> h2), pool accumulation, layer-3 transform
__global__ void __launch_bounds__(BLK) k_agg2(const __half* __restrict__ hwsB,
                                              const int* __restrict__ offs,
                                              const int* __restrict__ degi,
                                              const int* __restrict__ srcs,
                                              const float* __restrict__ dinv,
                                              const float* __restrict__ b2,
                                              const float* __restrict__ W3,
                                              float* __restrict__ hws3,
                                              float* __restrict__ pool, int n) {
    __shared__ float w3[16];
    __shared__ float bb[16];
    __shared__ float lp[16];
    int tid = threadIdx.x;
    if (tid < 16) { w3[tid] = W3[tid]; bb[tid] = b2[tid]; lp[tid] = 0.f; }
    __syncthreads();
    int nl = tid >> 2, sub = tid & 3;
    int i = blockIdx.x * 64 + nl;
    bool act = (i < n);
    float di = 0.f;
    float4 h = make_float4(0.f, 0.f, 0.f, 0.f);
    if (act) {
        di = dinv[i];
        GATHER4H(hwsB);
        h.x = fmaxf(di * acc.x + bb[sub * 4 + 0], 0.f);
        h.y = fmaxf(di * acc.y + bb[sub * 4 + 1], 0.f);
        h.z = fmaxf(di * acc.z + bb[sub * 4 + 2], 0.f);
        h.w = fmaxf(di * acc.w + bb[sub * 4 + 3], 0.f);
    }
    // hw3 = h . w3 (partial over this lane's 4 features, reduce across 4 lanes)
    float p = h.x * w3[sub * 4 + 0] + h.y * w3[sub * 4 + 1]
            + h.z * w3[sub * 4 + 2] + h.w * w3[sub * 4 + 3];
    p += __shfl_xor(p, 1);
    p += __shfl_xor(p, 2);
    if (act && sub == 0) hws3[i] = di * p;
    // pool: reduce h over the wave's 16 nodes (lanes stride 4 share features)
    float4 hp = h;
#pragma unroll
    for (int m = 4; m < 64; m <<= 1) {
        hp.x += __shfl_xor(hp.x, m);
        hp.y += __shfl_xor(hp.y, m);
        hp.z += __shfl_xor(hp.z, m);
        hp.w += __shfl_xor(hp.w, m);
    }
    if ((tid & 63) < 4) {                    // lane==sub holds wave sum
        atomicAdd(&lp[sub * 4 + 0], hp.x);
        atomicAdd(&lp[sub * 4 + 1], hp.y);
        atomicAdd(&lp[sub * 4 + 2], hp.z);
        atomicAdd(&lp[sub * 4 + 3], hp.w);
    }
    __syncthreads();
    if (tid < 16) atomicAdd(&pool[tid], lp[tid]);
}

// layer-3 aggregate -> logits c[n]; per-block max of masked logits
__global__ void __launch_bounds__(BLK) k_agg3(const float* __restrict__ hws3,
                                              const int* __restrict__ offs,
                                              const int* __restrict__ degi,
                                              const int* __restrict__ srcs,
                                              const float* __restrict__ dinv,
                                              const float* __restrict__ b3,
                                              const int* __restrict__ choices,
                                              float* __restrict__ cbuf,
                                              float* __restrict__ pmax, int n) {
    __shared__ float red[BLK];
    int tid = threadIdx.x;
    int nl = tid >> 2, sub = tid & 3;
    int i = blockIdx.x * 64 + nl;
    bool act = (i < n);
    float s = 0.f;
    if (act) {
        int beg = offs[i], end = beg + degi[i];
        for (int j = beg + sub; j < end; j += 4) s += hws3[srcs[j]];
    }
    s += __shfl_xor(s, 1);
    s += __shfl_xor(s, 2);
    float logit = -INFINITY;
    if (act && sub == 0) {
        float c = dinv[i] * (s + 2.f * hws3[i]) + b3[0];
        cbuf[i] = c;
        if (choices[i] != 0) logit = c;
    }
    red[tid] = logit;
    __syncthreads();
    for (int d = BLK / 2; d > 0; d >>= 1) {
        if (tid < d) red[tid] = fmaxf(red[tid], red[tid + d]);
        __syncthreads();
    }
    if (tid == 0) pmax[blockIdx.x] = red[0];
}

__global__ void k_redmax(const float* __restrict__ pmax, float* __restrict__ scal_m, int nblk) {
    __shared__ float red[BLK];
    float m = -INFINITY;
    for (int i = threadIdx.x; i < nblk; i += BLK) m = fmaxf(m, pmax[i]);
    red[threadIdx.x] = m;
    __syncthreads();
    for (int d = BLK / 2; d > 0; d >>= 1) {
        if (threadIdx.x < d) red[threadIdx.x] = fmaxf(red[threadIdx.x], red[threadIdx.x + d]);
        __syncthreads();
    }
    if (threadIdx.x == 0) scal_m[0] = red[0];
}

__global__ void __launch_bounds__(BLK) k_sumexp(const float* __restrict__ cbuf,
                                                const int* __restrict__ choices,
                                                const float* __restrict__ scal_m,
                                                float* __restrict__ Ssum, int n) {
    __shared__ float red[BLK];
    int i = blockIdx.x * BLK + threadIdx.x;
    float m = scal_m[0];
    float v = 0.0f;
    if (i < n && choices[i] != 0) v = expf(cbuf[i] - m);
    red[threadIdx.x] = v;
    __syncthreads();
    for (int d = BLK / 2; d > 0; d >>= 1) {
        if (threadIdx.x < d) red[threadIdx.x] += red[threadIdx.x + d];
        __syncthreads();
    }
    if (threadIdx.x == 0) atomicAdd(Ssum, red[0]);
}

__global__ void __launch_bounds__(BLK) k_final(const float* __restrict__ cbuf,
                                               const int* __restrict__ choices,
                                               const float* __restrict__ scal_m,
                                               const float* __restrict__ Ssum,
                                               const float* __restrict__ pool,
                                               const float* __restrict__ fcw,
                                               const float* __restrict__ fcb,
                                               float* __restrict__ out, int n) {
    int i = blockIdx.x * BLK + threadIdx.x;
    if (i < n) {
        float p = 0.0f;
        if (choices[i] != 0) {
            float m = scal_m[0], S = Ssum[0];
            p = expf(cbuf[i] - m) / S;
        }
        out[i] = p;
    }
    if (blockIdx.x == 0 && threadIdx.x == 0) {
        float invn = 1.0f / (float)n;
        float v = 0.0f;
#pragma unroll
        for (int f = 0; f < 16; f++) v += (pool[f] * invn) * fcw[f];
        out[n] = v + fcb[0];
    }
}

extern "C" void kernel_launch(void* const* d_in, const int* in_sizes, int n_in,
                              void* d_out, int out_size, void* d_ws, size_t ws_size,
                              hipStream_t stream) {
    const float* x       = (const float*)d_in[0];
    const int*   ei      = (const int*)d_in[1];
    const int*   choices = (const int*)d_in[2];
    const float* W1 = (const float*)d_in[3];
    const float* b1 = (const float*)d_in[4];
    const float* W2 = (const float*)d_in[5];
    const float* b2 = (const float*)d_in[6];
    const float* W3 = (const float*)d_in[7];
    const float* b3 = (const float*)d_in[8];
    const float* fcw = (const float*)d_in[9];
    const float* fcb = (const float*)d_in[10];
    float* out = (float*)d_out;

    int n = in_sizes[0] / 3;
    int E = in_sizes[1] / 2;
    const int* row = ei;
    const int* col = ei + E;

    int nblkN = (n + BLK - 1) / BLK;           // 391
    int nblk64 = (n + 63) / 64;                // 1563  (4 lanes/node kernels)
    int nbuck = (n + (1 << BSH) - 1) >> BSH;   // 196 buckets of 512 nodes
    int nblkBin = (E + EB - 1) / EB;           // 391 binning blocks

    // workspace layout (16B aligned slices)
    char* ws = (char*)d_ws;
    size_t o = 0;
    auto alloc = [&](size_t bytes) { char* p = ws + o; o += (bytes + 15) & ~(size_t)15; return p; };
    int*   degi   = (int*)  alloc((size_t)n * 4);
    int*   offs   = (int*)  alloc((size_t)n * 4);
    float* dinv   = (float*)alloc((size_t)n * 4);
    float* hws3   = (float*)alloc((size_t)n * 4);
    float* cbuf   = (float*)alloc((size_t)n * 4);
    float* pmax   = (float*)alloc(8192);       // >= nblk64 floats
    int*   bcnt   = (int*)  alloc(4096);
    int*   gcur   = (int*)  alloc(4096);
    int*   bbase  = (int*)  alloc(4096);
    float* scal   = (float*)alloc(256);   // [0]=S, [1..16]=pool, [17]=m
    float* Ssum   = scal + 0;
    float* pool   = scal + 1;
    float* scal_m = scal + 17;
    size_t hw_bytes = (size_t)n * 16 * 2 * 2;            // hwsA + hwsB (fp16)
    size_t pk_bytes = (size_t)E * 4;                     // packed (aliases hwsA/B)
    char*  blob   = alloc(hw_bytes > pk_bytes ? hw_bytes : pk_bytes);
    __half* hwsA  = (__half*)blob;
    __half* hwsB  = hwsA + (size_t)n * 16;
    int*   packed = (int*)blob;           // build phase only; dead before k_l1
    int*   srcs   = (int*)  alloc((size_t)E * 4);
    (void)ws_size;

    hipMemsetAsync(bcnt, 0, 1024, stream);
    hipMemsetAsync(scal, 0, 68, stream);   // S + pool[16]

    // ---- CSR build (no per-edge global atomics) ----
    k_bcount<<<nblkBin, BLK, 0, stream>>>(col, bcnt, E);
    k_bscan<<<1, 256, 0, stream>>>(bcnt, gcur, bbase, nbuck);
    k_bin<<<nblkBin, BINTH, 0, stream>>>(row, col, gcur, packed, E);
    k_place<<<nbuck, BLK, 0, stream>>>(packed, bbase, bcnt, degi, offs, dinv, srcs, n);

    // ---- GCN layers (4 lanes per node, fp16 payloads) ----
    k_l1<<<nblkN, BLK, 0, stream>>>(x, W1, dinv, hwsA, n);
    k_agg1<<<nblk64, BLK, 0, stream>>>(hwsA, offs, degi, srcs, dinv, b1, W2, hwsB, n);
    k_agg2<<<nblk64, BLK, 0, stream>>>(hwsB, offs, degi, srcs, dinv, b2, W3, hws3, pool, n);
    k_agg3<<<nblk64, BLK, 0, stream>>>(hws3, offs, degi, srcs, dinv, b3, choices, cbuf, pmax, n);

    // ---- softmax + value head ----
    k_redmax<<<1, BLK, 0, stream>>>(pmax, scal_m, nblk64);
    k_sumexp<<<nblkN, BLK, 0, stream>>>(cbuf, choices, scal_m, Ssum, n);
    k_final<<<nblkN, BLK, 0, stream>>>(cbuf, choices, scal_m, Ssum, pool, fcw, fcb, out, n);
}